// Round 1
// baseline (452.382 us; speedup 1.0000x reference)
//
#include <hip/hip_runtime.h>
#include <hip/hip_bf16.h>

// ---------------- graph prep ----------------

__global__ void count_kernel(const int* __restrict__ dst, int E, int* __restrict__ counts) {
    int e = blockIdx.x * blockDim.x + threadIdx.x;
    if (e < E) atomicAdd(&counts[dst[e]], 1);
}

__global__ void dinv_kernel(const int* __restrict__ counts, float* __restrict__ dinv, int n) {
    int i = blockIdx.x * blockDim.x + threadIdx.x;
    if (i < n) dinv[i] = rsqrtf(1.0f + (float)counts[i]);   // +1 self loop
}

// single-block exclusive scan (n ~ 50000), writes rowptr[0..n] and cursor[0..n-1]
__global__ void scan_kernel(const int* __restrict__ counts, int* __restrict__ rowptr,
                            int* __restrict__ cursor, int n) {
    __shared__ int sums[256];
    int t = threadIdx.x;
    int chunk = (n + 255) >> 8;
    int lo = t * chunk, hi = min(n, lo + chunk);
    int s = 0;
    for (int i = lo; i < hi; ++i) s += counts[i];
    sums[t] = s;
    __syncthreads();
    // Hillis-Steele inclusive scan over 256 partials
    for (int off = 1; off < 256; off <<= 1) {
        int v = (t >= off) ? sums[t - off] : 0;
        __syncthreads();
        sums[t] += v;
        __syncthreads();
    }
    int offset = (t == 0) ? 0 : sums[t - 1];
    for (int i = lo; i < hi; ++i) {
        rowptr[i] = offset;
        cursor[i] = offset;
        offset += counts[i];
    }
    if (t == 255) rowptr[n] = offset;
}

__global__ void fill_kernel(const int* __restrict__ src, const int* __restrict__ dst, int E,
                            const float* __restrict__ dinv, int* __restrict__ cursor,
                            int* __restrict__ col, float* __restrict__ wv) {
    int e = blockIdx.x * blockDim.x + threadIdx.x;
    if (e < E) {
        int s = src[e], d = dst[e];
        int p = atomicAdd(&cursor[d], 1);
        col[p] = s;
        wv[p]  = dinv[s] * dinv[d];
    }
}

// ---------------- GEMM: C[n][dout] = X[n][128] @ W[128][dout] ----------------
// tile 64 rows x 64 cols, K chunked by 32 through LDS; 4x4 micro-tile per thread.
__global__ __launch_bounds__(256) void gemm_k128(const float* __restrict__ X,
                                                 const float* __restrict__ W,
                                                 float* __restrict__ C, int n, int dout) {
    __shared__ float Xs[64][36];   // [row][k-in-chunk], +4 pad (bank spread)
    __shared__ float Ws[32][64];   // [k-in-chunk][col]
    const int t  = threadIdx.x;
    const int tx = t & 15;         // col group (4 cols)
    const int ty = t >> 4;         // row group (4 rows)
    const int row0 = blockIdx.y * 64;
    const int col0 = blockIdx.x * 64;

    float acc[4][4];
#pragma unroll
    for (int i = 0; i < 4; ++i)
#pragma unroll
        for (int j = 0; j < 4; ++j) acc[i][j] = 0.0f;

    for (int kc = 0; kc < 4; ++kc) {
        // stage X chunk: 64 rows x 32 k = 512 float4, 2 per thread
#pragma unroll
        for (int i = 0; i < 2; ++i) {
            int idx = t + i * 256;          // 0..511
            int r   = idx >> 3;             // 0..63
            int k4  = idx & 7;              // 0..7 (float4 along k)
            int gr  = row0 + r;
            float4 v = make_float4(0.f, 0.f, 0.f, 0.f);
            if (gr < n) v = *(const float4*)&X[(size_t)gr * 128 + kc * 32 + k4 * 4];
            *(float4*)&Xs[r][k4 * 4] = v;
        }
        // stage W chunk: 32 k x 64 cols = 512 float4, 2 per thread
#pragma unroll
        for (int i = 0; i < 2; ++i) {
            int idx = t + i * 256;
            int k   = idx >> 4;             // 0..31
            int c4  = idx & 15;             // 0..15
            float4 v = *(const float4*)&W[(size_t)(kc * 32 + k) * dout + col0 + c4 * 4];
            *(float4*)&Ws[k][c4 * 4] = v;
        }
        __syncthreads();
#pragma unroll 8
        for (int k = 0; k < 32; ++k) {
            float4 wv4 = *(const float4*)&Ws[k][tx * 4];
            float x0 = Xs[ty * 4 + 0][k];
            float x1 = Xs[ty * 4 + 1][k];
            float x2 = Xs[ty * 4 + 2][k];
            float x3 = Xs[ty * 4 + 3][k];
            acc[0][0] += x0 * wv4.x; acc[0][1] += x0 * wv4.y; acc[0][2] += x0 * wv4.z; acc[0][3] += x0 * wv4.w;
            acc[1][0] += x1 * wv4.x; acc[1][1] += x1 * wv4.y; acc[1][2] += x1 * wv4.z; acc[1][3] += x1 * wv4.w;
            acc[2][0] += x2 * wv4.x; acc[2][1] += x2 * wv4.y; acc[2][2] += x2 * wv4.z; acc[2][3] += x2 * wv4.w;
            acc[3][0] += x3 * wv4.x; acc[3][1] += x3 * wv4.y; acc[3][2] += x3 * wv4.z; acc[3][3] += x3 * wv4.w;
        }
        __syncthreads();
    }
#pragma unroll
    for (int i = 0; i < 4; ++i) {
        int gr = row0 + ty * 4 + i;
        if (gr < n) {
            float4 o = make_float4(acc[i][0], acc[i][1], acc[i][2], acc[i][3]);
            *(float4*)&C[(size_t)gr * dout + col0 + tx * 4] = o;
        }
    }
}

// ---------------- aggregation (CSR gather): out[i] = b + H[i]*dinv[i]^2 + sum_j w*H[col] ----------------
template <int DOUT, bool RELU>
__global__ __launch_bounds__(256) void agg_kernel(const float* __restrict__ H,
                                                  const int* __restrict__ rowptr,
                                                  const int* __restrict__ col,
                                                  const float* __restrict__ wv,
                                                  const float* __restrict__ dinv,
                                                  const float* __restrict__ bias,
                                                  float* __restrict__ out, int n) {
    constexpr int LPR = DOUT / 4;        // lanes per row
    constexpr int RPB = 256 / LPR;       // rows per block
    int row  = blockIdx.x * RPB + threadIdx.x / LPR;
    int lane = threadIdx.x % LPR;
    if (row >= n) return;

    const float4* Hv = (const float4*)H;
    float4 h0 = Hv[(size_t)row * LPR + lane];
    float4 bv = ((const float4*)bias)[lane];
    float  di = dinv[row];
    float  sw = di * di;
    float a0 = bv.x + h0.x * sw;
    float a1 = bv.y + h0.y * sw;
    float a2 = bv.z + h0.z * sw;
    float a3 = bv.w + h0.w * sw;

    int j  = rowptr[row];
    int je = rowptr[row + 1];
    for (; j + 1 < je; j += 2) {
        int   c0 = col[j],  c1 = col[j + 1];
        float w0 = wv[j],   w1 = wv[j + 1];
        float4 v0 = Hv[(size_t)c0 * LPR + lane];
        float4 v1 = Hv[(size_t)c1 * LPR + lane];
        a0 += w0 * v0.x + w1 * v1.x;
        a1 += w0 * v0.y + w1 * v1.y;
        a2 += w0 * v0.z + w1 * v1.z;
        a3 += w0 * v0.w + w1 * v1.w;
    }
    if (j < je) {
        int   c0 = col[j];
        float w0 = wv[j];
        float4 v0 = Hv[(size_t)c0 * LPR + lane];
        a0 += w0 * v0.x; a1 += w0 * v0.y; a2 += w0 * v0.z; a3 += w0 * v0.w;
    }
    if (RELU) {
        a0 = fmaxf(a0, 0.f); a1 = fmaxf(a1, 0.f); a2 = fmaxf(a2, 0.f); a3 = fmaxf(a3, 0.f);
    }
    float4 o = make_float4(a0, a1, a2, a3);
    ((float4*)out)[(size_t)row * LPR + lane] = o;
}

// ---------------- log_softmax over 64 cols, one wave per row ----------------
__global__ __launch_bounds__(256) void logsoftmax_kernel(float* __restrict__ out, int n) {
    int row  = blockIdx.x * 4 + (threadIdx.x >> 6);
    int lane = threadIdx.x & 63;
    if (row >= n) return;
    float x = out[(size_t)row * 64 + lane];
    float m = x;
#pragma unroll
    for (int off = 32; off >= 1; off >>= 1) m = fmaxf(m, __shfl_xor(m, off, 64));
    float ex = expf(x - m);
    float s  = ex;
#pragma unroll
    for (int off = 32; off >= 1; off >>= 1) s += __shfl_xor(s, off, 64);
    out[(size_t)row * 64 + lane] = x - m - logf(s);
}

// ---------------- launch ----------------

extern "C" void kernel_launch(void* const* d_in, const int* in_sizes, int n_in,
                              void* d_out, int out_size, void* d_ws, size_t ws_size,
                              hipStream_t stream) {
    const float* X  = (const float*)d_in[0];
    const int*   ei = (const int*)d_in[1];     // [2][E], int32 per harness convention
    const float* W1 = (const float*)d_in[2];
    const float* b1 = (const float*)d_in[3];
    const float* W2 = (const float*)d_in[4];
    const float* b2 = (const float*)d_in[5];

    const int n = in_sizes[0] / 128;           // 50000
    const int E = in_sizes[1] / 2;             // 800000
    const int* src = ei;
    const int* dst = ei + E;

    char* ws = (char*)d_ws;
    size_t off = 0;
    auto alloc = [&](size_t bytes) -> void* {
        void* p = ws + off;
        off = (off + bytes + 255) & ~(size_t)255;
        return p;
    };
    float* dinv   = (float*)alloc((size_t)n * 4);
    int*   counts = (int*)  alloc((size_t)n * 4);
    int*   rowptr = (int*)  alloc((size_t)(n + 1) * 4);
    int*   cursor = (int*)  alloc((size_t)n * 4);
    int*   colv   = (int*)  alloc((size_t)E * 4);
    float* wv     = (float*)alloc((size_t)E * 4);
    float* A      = (float*)alloc((size_t)n * 128 * 4);
    float* B      = (float*)alloc((size_t)n * 128 * 4);

    // --- graph prep (per call; deterministic work) ---
    hipMemsetAsync(counts, 0, (size_t)n * 4, stream);
    count_kernel<<<(E + 255) / 256, 256, 0, stream>>>(dst, E, counts);
    dinv_kernel<<<(n + 255) / 256, 256, 0, stream>>>(counts, dinv, n);
    scan_kernel<<<1, 256, 0, stream>>>(counts, rowptr, cursor, n);
    fill_kernel<<<(E + 255) / 256, 256, 0, stream>>>(src, dst, E, dinv, cursor, colv, wv);

    // --- layer 1: A = X@W1 ; B = agg(A) + b1 ---
    dim3 g1(128 / 64, (n + 63) / 64);
    gemm_k128<<<g1, 256, 0, stream>>>(X, W1, A, n, 128);
    agg_kernel<128, false><<<(n + 7) / 8, 256, 0, stream>>>(A, rowptr, colv, wv, dinv, b1, B, n);

    // --- layer 2: A = B@W1 ; B = relu(agg(A) + b1) ---
    gemm_k128<<<g1, 256, 0, stream>>>(B, W1, A, n, 128);
    agg_kernel<128, true><<<(n + 7) / 8, 256, 0, stream>>>(A, rowptr, colv, wv, dinv, b1, B, n);

    // --- layer 3: A = B@W2 (n x 64) ; d_out = agg(A) + b2 ; log_softmax in place ---
    dim3 g2(64 / 64, (n + 63) / 64);
    gemm_k128<<<g2, 256, 0, stream>>>(B, W2, A, n, 64);
    agg_kernel<64, false><<<(n + 15) / 16, 256, 0, stream>>>(A, rowptr, colv, wv, dinv, b2,
                                                             (float*)d_out, n);
    logsoftmax_kernel<<<(n + 3) / 4, 256, 0, stream>>>((float*)d_out, n);
}

// Round 2
// 343.519 us; speedup vs baseline: 1.3169x; 1.3169x over previous
//
#include <hip/hip_runtime.h>
#include <hip/hip_bf16.h>

// ---------------- graph prep ----------------

__global__ void count_kernel(const int* __restrict__ dst, int E, int* __restrict__ counts) {
    int e = blockIdx.x * blockDim.x + threadIdx.x;
    if (e < E) atomicAdd(&counts[dst[e]], 1);
}

__global__ void dinv_kernel(const int* __restrict__ counts, float* __restrict__ dinv, int n) {
    int i = blockIdx.x * blockDim.x + threadIdx.x;
    if (i < n) dinv[i] = rsqrtf(1.0f + (float)counts[i]);   // +1 self loop
}

// ---- 3-phase device-wide exclusive scan over counts[0..n) ----

__global__ __launch_bounds__(256) void block_sum_kernel(const int* __restrict__ counts, int n,
                                                        int* __restrict__ blocksums) {
    __shared__ int s[256];
    int t = threadIdx.x;
    int i = blockIdx.x * 256 + t;
    s[t] = (i < n) ? counts[i] : 0;
    __syncthreads();
#pragma unroll
    for (int off = 128; off >= 1; off >>= 1) {
        if (t < off) s[t] += s[t + off];
        __syncthreads();
    }
    if (t == 0) blocksums[blockIdx.x] = s[0];
}

// single block; nb <= 256
__global__ __launch_bounds__(256) void scan_blocksums_kernel(int* __restrict__ blocksums, int nb) {
    __shared__ int s[256];
    int t = threadIdx.x;
    int v = (t < nb) ? blocksums[t] : 0;
    s[t] = v;
    __syncthreads();
    for (int off = 1; off < 256; off <<= 1) {
        int u = (t >= off) ? s[t - off] : 0;
        __syncthreads();
        s[t] += u;
        __syncthreads();
    }
    if (t < nb) blocksums[t] = s[t] - v;   // exclusive prefix of block sums
}

__global__ __launch_bounds__(256) void scan_write_kernel(const int* __restrict__ counts,
                                                         const int* __restrict__ blockoff, int n,
                                                         int* __restrict__ rowptr,
                                                         int* __restrict__ cursor) {
    __shared__ int s[256];
    int t = threadIdx.x;
    int i = blockIdx.x * 256 + t;
    int v = (i < n) ? counts[i] : 0;
    s[t] = v;
    __syncthreads();
    for (int off = 1; off < 256; off <<= 1) {
        int u = (t >= off) ? s[t - off] : 0;
        __syncthreads();
        s[t] += u;
        __syncthreads();
    }
    int excl = blockoff[blockIdx.x] + s[t] - v;
    if (i < n) {
        rowptr[i] = excl;
        cursor[i] = excl;
        if (i == n - 1) rowptr[n] = excl + v;
    }
}

__global__ void fill_kernel(const int* __restrict__ src, const int* __restrict__ dst, int E,
                            const float* __restrict__ dinv, int* __restrict__ cursor,
                            int* __restrict__ col, float* __restrict__ wv) {
    int e = blockIdx.x * blockDim.x + threadIdx.x;
    if (e < E) {
        int s = src[e], d = dst[e];
        int p = atomicAdd(&cursor[d], 1);
        col[p] = s;
        wv[p]  = dinv[s] * dinv[d];
    }
}

// ---------------- GEMM: C[n][dout] = X[n][128] @ W[128][dout] ----------------
// tile 64 rows x 64 cols, K chunked by 32 through LDS; 4x4 micro-tile per thread.
__global__ __launch_bounds__(256) void gemm_k128(const float* __restrict__ X,
                                                 const float* __restrict__ W,
                                                 float* __restrict__ C, int n, int dout) {
    __shared__ float Xs[64][36];   // [row][k-in-chunk], +4 pad (bank spread)
    __shared__ float Ws[32][64];   // [k-in-chunk][col]
    const int t  = threadIdx.x;
    const int tx = t & 15;         // col group (4 cols)
    const int ty = t >> 4;         // row group (4 rows)
    const int row0 = blockIdx.y * 64;
    const int col0 = blockIdx.x * 64;

    float acc[4][4];
#pragma unroll
    for (int i = 0; i < 4; ++i)
#pragma unroll
        for (int j = 0; j < 4; ++j) acc[i][j] = 0.0f;

    for (int kc = 0; kc < 4; ++kc) {
        // stage X chunk: 64 rows x 32 k = 512 float4, 2 per thread
#pragma unroll
        for (int i = 0; i < 2; ++i) {
            int idx = t + i * 256;          // 0..511
            int r   = idx >> 3;             // 0..63
            int k4  = idx & 7;              // 0..7 (float4 along k)
            int gr  = row0 + r;
            float4 v = make_float4(0.f, 0.f, 0.f, 0.f);
            if (gr < n) v = *(const float4*)&X[(size_t)gr * 128 + kc * 32 + k4 * 4];
            *(float4*)&Xs[r][k4 * 4] = v;
        }
        // stage W chunk: 32 k x 64 cols = 512 float4, 2 per thread
#pragma unroll
        for (int i = 0; i < 2; ++i) {
            int idx = t + i * 256;
            int k   = idx >> 4;             // 0..31
            int c4  = idx & 15;             // 0..15
            float4 v = *(const float4*)&W[(size_t)(kc * 32 + k) * dout + col0 + c4 * 4];
            *(float4*)&Ws[k][c4 * 4] = v;
        }
        __syncthreads();
#pragma unroll 8
        for (int k = 0; k < 32; ++k) {
            float4 wv4 = *(const float4*)&Ws[k][tx * 4];
            float x0 = Xs[ty * 4 + 0][k];
            float x1 = Xs[ty * 4 + 1][k];
            float x2 = Xs[ty * 4 + 2][k];
            float x3 = Xs[ty * 4 + 3][k];
            acc[0][0] += x0 * wv4.x; acc[0][1] += x0 * wv4.y; acc[0][2] += x0 * wv4.z; acc[0][3] += x0 * wv4.w;
            acc[1][0] += x1 * wv4.x; acc[1][1] += x1 * wv4.y; acc[1][2] += x1 * wv4.z; acc[1][3] += x1 * wv4.w;
            acc[2][0] += x2 * wv4.x; acc[2][1] += x2 * wv4.y; acc[2][2] += x2 * wv4.z; acc[2][3] += x2 * wv4.w;
            acc[3][0] += x3 * wv4.x; acc[3][1] += x3 * wv4.y; acc[3][2] += x3 * wv4.z; acc[3][3] += x3 * wv4.w;
        }
        __syncthreads();
    }
#pragma unroll
    for (int i = 0; i < 4; ++i) {
        int gr = row0 + ty * 4 + i;
        if (gr < n) {
            float4 o = make_float4(acc[i][0], acc[i][1], acc[i][2], acc[i][3]);
            *(float4*)&C[(size_t)gr * dout + col0 + tx * 4] = o;
        }
    }
}

// ---------------- aggregation (CSR gather): out[i] = b + H[i]*dinv[i]^2 + sum_j w*H[col] ----------------
template <int DOUT, bool RELU>
__global__ __launch_bounds__(256) void agg_kernel(const float* __restrict__ H,
                                                  const int* __restrict__ rowptr,
                                                  const int* __restrict__ col,
                                                  const float* __restrict__ wv,
                                                  const float* __restrict__ dinv,
                                                  const float* __restrict__ bias,
                                                  float* __restrict__ out, int n) {
    constexpr int LPR = DOUT / 4;        // lanes per row
    constexpr int RPB = 256 / LPR;       // rows per block
    int row  = blockIdx.x * RPB + threadIdx.x / LPR;
    int lane = threadIdx.x % LPR;
    if (row >= n) return;

    const float4* Hv = (const float4*)H;
    float4 h0 = Hv[(size_t)row * LPR + lane];
    float4 bv = ((const float4*)bias)[lane];
    float  di = dinv[row];
    float  sw = di * di;
    float a0 = bv.x + h0.x * sw;
    float a1 = bv.y + h0.y * sw;
    float a2 = bv.z + h0.z * sw;
    float a3 = bv.w + h0.w * sw;

    int j  = rowptr[row];
    int je = rowptr[row + 1];
    for (; j + 1 < je; j += 2) {
        int   c0 = col[j],  c1 = col[j + 1];
        float w0 = wv[j],   w1 = wv[j + 1];
        float4 v0 = Hv[(size_t)c0 * LPR + lane];
        float4 v1 = Hv[(size_t)c1 * LPR + lane];
        a0 += w0 * v0.x + w1 * v1.x;
        a1 += w0 * v0.y + w1 * v1.y;
        a2 += w0 * v0.z + w1 * v1.z;
        a3 += w0 * v0.w + w1 * v1.w;
    }
    if (j < je) {
        int   c0 = col[j];
        float w0 = wv[j];
        float4 v0 = Hv[(size_t)c0 * LPR + lane];
        a0 += w0 * v0.x; a1 += w0 * v0.y; a2 += w0 * v0.z; a3 += w0 * v0.w;
    }
    if (RELU) {
        a0 = fmaxf(a0, 0.f); a1 = fmaxf(a1, 0.f); a2 = fmaxf(a2, 0.f); a3 = fmaxf(a3, 0.f);
    }
    float4 o = make_float4(a0, a1, a2, a3);
    ((float4*)out)[(size_t)row * LPR + lane] = o;
}

// ---------------- log_softmax over 64 cols, one wave per row ----------------
__global__ __launch_bounds__(256) void logsoftmax_kernel(float* __restrict__ out, int n) {
    int row  = blockIdx.x * 4 + (threadIdx.x >> 6);
    int lane = threadIdx.x & 63;
    if (row >= n) return;
    float x = out[(size_t)row * 64 + lane];
    float m = x;
#pragma unroll
    for (int off = 32; off >= 1; off >>= 1) m = fmaxf(m, __shfl_xor(m, off, 64));
    float ex = expf(x - m);
    float s  = ex;
#pragma unroll
    for (int off = 32; off >= 1; off >>= 1) s += __shfl_xor(s, off, 64);
    out[(size_t)row * 64 + lane] = x - m - logf(s);
}

// ---------------- launch ----------------

extern "C" void kernel_launch(void* const* d_in, const int* in_sizes, int n_in,
                              void* d_out, int out_size, void* d_ws, size_t ws_size,
                              hipStream_t stream) {
    const float* X  = (const float*)d_in[0];
    const int*   ei = (const int*)d_in[1];     // [2][E], int32 per harness convention
    const float* W1 = (const float*)d_in[2];
    const float* b1 = (const float*)d_in[3];
    const float* W2 = (const float*)d_in[4];
    const float* b2 = (const float*)d_in[5];

    const int n = in_sizes[0] / 128;           // 50000
    const int E = in_sizes[1] / 2;             // 800000
    const int* src = ei;
    const int* dst = ei + E;

    char* ws = (char*)d_ws;
    size_t off = 0;
    auto alloc = [&](size_t bytes) -> void* {
        void* p = ws + off;
        off = (off + bytes + 255) & ~(size_t)255;
        return p;
    };
    float* dinv    = (float*)alloc((size_t)n * 4);
    int*   counts  = (int*)  alloc((size_t)n * 4);
    int*   rowptr  = (int*)  alloc((size_t)(n + 1) * 4);
    int*   cursor  = (int*)  alloc((size_t)n * 4);
    int*   bsums   = (int*)  alloc(256 * 4);
    int*   colv    = (int*)  alloc((size_t)E * 4);
    float* wv      = (float*)alloc((size_t)E * 4);
    float* A       = (float*)alloc((size_t)n * 128 * 4);
    float* B       = (float*)alloc((size_t)n * 128 * 4);

    const int nb = (n + 255) / 256;            // 196 scan blocks

    // --- graph prep (per call; deterministic work) ---
    hipMemsetAsync(counts, 0, (size_t)n * 4, stream);
    count_kernel<<<(E + 255) / 256, 256, 0, stream>>>(dst, E, counts);
    dinv_kernel<<<(n + 255) / 256, 256, 0, stream>>>(counts, dinv, n);
    block_sum_kernel<<<nb, 256, 0, stream>>>(counts, n, bsums);
    scan_blocksums_kernel<<<1, 256, 0, stream>>>(bsums, nb);
    scan_write_kernel<<<nb, 256, 0, stream>>>(counts, bsums, n, rowptr, cursor);
    fill_kernel<<<(E + 255) / 256, 256, 0, stream>>>(src, dst, E, dinv, cursor, colv, wv);

    // --- layer 1: A = X@W1 ; B = agg(A) + b1 ---
    dim3 g1(128 / 64, (n + 63) / 64);
    gemm_k128<<<g1, 256, 0, stream>>>(X, W1, A, n, 128);
    agg_kernel<128, false><<<(n + 7) / 8, 256, 0, stream>>>(A, rowptr, colv, wv, dinv, b1, B, n);

    // --- layer 2: A = B@W1 ; B = relu(agg(A) + b1) ---
    gemm_k128<<<g1, 256, 0, stream>>>(B, W1, A, n, 128);
    agg_kernel<128, true><<<(n + 7) / 8, 256, 0, stream>>>(A, rowptr, colv, wv, dinv, b1, B, n);

    // --- layer 3: A = B@W2 (n x 64) ; d_out = agg(A) + b2 ; log_softmax in place ---
    dim3 g2(64 / 64, (n + 63) / 64);
    gemm_k128<<<g2, 256, 0, stream>>>(B, W2, A, n, 64);
    agg_kernel<64, false><<<(n + 15) / 16, 256, 0, stream>>>(A, rowptr, colv, wv, dinv, b2,
                                                             (float*)d_out, n);
    logsoftmax_kernel<<<(n + 3) / 4, 256, 0, stream>>>((float*)d_out, n);
}

// Round 3
// 284.481 us; speedup vs baseline: 1.5902x; 1.2075x over previous
//
#include <hip/hip_runtime.h>
#include <hip/hip_bf16.h>
#include <hip/hip_fp16.h>

// ---------------- graph prep ----------------

__global__ void count_kernel(const int* __restrict__ dst, int E, int* __restrict__ counts) {
    int e = blockIdx.x * blockDim.x + threadIdx.x;
    if (e < E) atomicAdd(&counts[dst[e]], 1);
}

__global__ void dinv_kernel(const int* __restrict__ counts, float* __restrict__ dinv, int n) {
    int i = blockIdx.x * blockDim.x + threadIdx.x;
    if (i < n) dinv[i] = rsqrtf(1.0f + (float)counts[i]);   // +1 self loop
}

// ---- 3-phase device-wide exclusive scan over counts[0..n) ----

__global__ __launch_bounds__(256) void block_sum_kernel(const int* __restrict__ counts, int n,
                                                        int* __restrict__ blocksums) {
    __shared__ int s[256];
    int t = threadIdx.x;
    int i = blockIdx.x * 256 + t;
    s[t] = (i < n) ? counts[i] : 0;
    __syncthreads();
#pragma unroll
    for (int off = 128; off >= 1; off >>= 1) {
        if (t < off) s[t] += s[t + off];
        __syncthreads();
    }
    if (t == 0) blocksums[blockIdx.x] = s[0];
}

// single block; nb <= 256
__global__ __launch_bounds__(256) void scan_blocksums_kernel(int* __restrict__ blocksums, int nb) {
    __shared__ int s[256];
    int t = threadIdx.x;
    int v = (t < nb) ? blocksums[t] : 0;
    s[t] = v;
    __syncthreads();
    for (int off = 1; off < 256; off <<= 1) {
        int u = (t >= off) ? s[t - off] : 0;
        __syncthreads();
        s[t] += u;
        __syncthreads();
    }
    if (t < nb) blocksums[t] = s[t] - v;   // exclusive prefix of block sums
}

__global__ __launch_bounds__(256) void scan_write_kernel(const int* __restrict__ counts,
                                                         const int* __restrict__ blockoff, int n,
                                                         int* __restrict__ rowptr,
                                                         int* __restrict__ cursor) {
    __shared__ int s[256];
    int t = threadIdx.x;
    int i = blockIdx.x * 256 + t;
    int v = (i < n) ? counts[i] : 0;
    s[t] = v;
    __syncthreads();
    for (int off = 1; off < 256; off <<= 1) {
        int u = (t >= off) ? s[t - off] : 0;
        __syncthreads();
        s[t] += u;
        __syncthreads();
    }
    int excl = blockoff[blockIdx.x] + s[t] - v;
    if (i < n) {
        rowptr[i] = excl;
        cursor[i] = excl;
        if (i == n - 1) rowptr[n] = excl + v;
    }
}

// packed edge record: .x = src index, .y = bit-cast fp32 weight (one 8B scattered write)
__global__ void fill_kernel(const int* __restrict__ src, const int* __restrict__ dst, int E,
                            const float* __restrict__ dinv, int* __restrict__ cursor,
                            int2* __restrict__ edges) {
    int e = blockIdx.x * blockDim.x + threadIdx.x;
    if (e < E) {
        int s = src[e], d = dst[e];
        int p = atomicAdd(&cursor[d], 1);
        edges[p] = make_int2(s, __float_as_int(dinv[s] * dinv[d]));
    }
}

// ---------------- GEMM: C[n][dout](fp16) = X[n][128](fp32) @ W[128][dout](fp32) ----------------
// tile 64 rows x 64 cols, K chunked by 32 through LDS; 4x4 micro-tile per thread.
__global__ __launch_bounds__(256) void gemm_k128(const float* __restrict__ X,
                                                 const float* __restrict__ W,
                                                 __half* __restrict__ C, int n, int dout) {
    __shared__ float Xs[64][36];   // [row][k-in-chunk], +4 pad (bank spread)
    __shared__ float Ws[32][64];   // [k-in-chunk][col]
    const int t  = threadIdx.x;
    const int tx = t & 15;         // col group (4 cols)
    const int ty = t >> 4;         // row group (4 rows)
    const int row0 = blockIdx.y * 64;
    const int col0 = blockIdx.x * 64;

    float acc[4][4];
#pragma unroll
    for (int i = 0; i < 4; ++i)
#pragma unroll
        for (int j = 0; j < 4; ++j) acc[i][j] = 0.0f;

    for (int kc = 0; kc < 4; ++kc) {
#pragma unroll
        for (int i = 0; i < 2; ++i) {
            int idx = t + i * 256;          // 0..511
            int r   = idx >> 3;             // 0..63
            int k4  = idx & 7;              // 0..7 (float4 along k)
            int gr  = row0 + r;
            float4 v = make_float4(0.f, 0.f, 0.f, 0.f);
            if (gr < n) v = *(const float4*)&X[(size_t)gr * 128 + kc * 32 + k4 * 4];
            *(float4*)&Xs[r][k4 * 4] = v;
        }
#pragma unroll
        for (int i = 0; i < 2; ++i) {
            int idx = t + i * 256;
            int k   = idx >> 4;             // 0..31
            int c4  = idx & 15;             // 0..15
            float4 v = *(const float4*)&W[(size_t)(kc * 32 + k) * dout + col0 + c4 * 4];
            *(float4*)&Ws[k][c4 * 4] = v;
        }
        __syncthreads();
#pragma unroll 8
        for (int k = 0; k < 32; ++k) {
            float4 wv4 = *(const float4*)&Ws[k][tx * 4];
            float x0 = Xs[ty * 4 + 0][k];
            float x1 = Xs[ty * 4 + 1][k];
            float x2 = Xs[ty * 4 + 2][k];
            float x3 = Xs[ty * 4 + 3][k];
            acc[0][0] += x0 * wv4.x; acc[0][1] += x0 * wv4.y; acc[0][2] += x0 * wv4.z; acc[0][3] += x0 * wv4.w;
            acc[1][0] += x1 * wv4.x; acc[1][1] += x1 * wv4.y; acc[1][2] += x1 * wv4.z; acc[1][3] += x1 * wv4.w;
            acc[2][0] += x2 * wv4.x; acc[2][1] += x2 * wv4.y; acc[2][2] += x2 * wv4.z; acc[2][3] += x2 * wv4.w;
            acc[3][0] += x3 * wv4.x; acc[3][1] += x3 * wv4.y; acc[3][2] += x3 * wv4.z; acc[3][3] += x3 * wv4.w;
        }
        __syncthreads();
    }
#pragma unroll
    for (int i = 0; i < 4; ++i) {
        int gr = row0 + ty * 4 + i;
        if (gr < n) {
            __half2 p0 = __floats2half2_rn(acc[i][0], acc[i][1]);
            __half2 p1 = __floats2half2_rn(acc[i][2], acc[i][3]);
            float2 o;
            o.x = *(float*)&p0;
            o.y = *(float*)&p1;
            *(float2*)&C[(size_t)gr * dout + col0 + tx * 4] = o;
        }
    }
}

// ---------------- aggregation (CSR gather, fp16 operand): out[i] = b + H[i]*dinv_i^2 + sum_j w*H[col] ----------------
template <int DOUT, bool RELU>
__global__ __launch_bounds__(256) void agg_kernel(const __half* __restrict__ H,
                                                  const int* __restrict__ rowptr,
                                                  const int2* __restrict__ edges,
                                                  const float* __restrict__ dinv,
                                                  const float* __restrict__ bias,
                                                  float* __restrict__ out, int n) {
    constexpr int LPR = DOUT / 4;        // lanes per row (4 halfs = 8B per lane)
    constexpr int RPB = 256 / LPR;       // rows per block
    int row  = blockIdx.x * RPB + threadIdx.x / LPR;
    int lane = threadIdx.x % LPR;
    if (row >= n) return;

    const float2* Hv = (const float2*)H;   // 8B = 4 halfs
    auto cvt4 = [](float2 raw, float& f0, float& f1, float& f2, float& f3) {
        __half2 h01 = *(__half2*)&raw.x;
        __half2 h23 = *(__half2*)&raw.y;
        float2 a = __half22float2(h01);
        float2 b = __half22float2(h23);
        f0 = a.x; f1 = a.y; f2 = b.x; f3 = b.y;
    };

    float4 bv = ((const float4*)bias)[lane];
    float  di = dinv[row];
    float  sw = di * di;
    float h0, h1, h2, h3;
    cvt4(Hv[(size_t)row * LPR + lane], h0, h1, h2, h3);
    float a0 = bv.x + h0 * sw;
    float a1 = bv.y + h1 * sw;
    float a2 = bv.z + h2 * sw;
    float a3 = bv.w + h3 * sw;

    int j  = rowptr[row];
    int je = rowptr[row + 1];
    for (; j + 1 < je; j += 2) {
        int2 e0 = edges[j];
        int2 e1 = edges[j + 1];
        float w0 = __int_as_float(e0.y);
        float w1 = __int_as_float(e1.y);
        float v00, v01, v02, v03, v10, v11, v12, v13;
        cvt4(Hv[(size_t)e0.x * LPR + lane], v00, v01, v02, v03);
        cvt4(Hv[(size_t)e1.x * LPR + lane], v10, v11, v12, v13);
        a0 += w0 * v00 + w1 * v10;
        a1 += w0 * v01 + w1 * v11;
        a2 += w0 * v02 + w1 * v12;
        a3 += w0 * v03 + w1 * v13;
    }
    if (j < je) {
        int2 e0 = edges[j];
        float w0 = __int_as_float(e0.y);
        float v00, v01, v02, v03;
        cvt4(Hv[(size_t)e0.x * LPR + lane], v00, v01, v02, v03);
        a0 += w0 * v00; a1 += w0 * v01; a2 += w0 * v02; a3 += w0 * v03;
    }
    if (RELU) {
        a0 = fmaxf(a0, 0.f); a1 = fmaxf(a1, 0.f); a2 = fmaxf(a2, 0.f); a3 = fmaxf(a3, 0.f);
    }
    ((float4*)out)[(size_t)row * LPR + lane] = make_float4(a0, a1, a2, a3);
}

// ---------------- log_softmax over 64 cols, one wave per row ----------------
__global__ __launch_bounds__(256) void logsoftmax_kernel(float* __restrict__ out, int n) {
    int row  = blockIdx.x * 4 + (threadIdx.x >> 6);
    int lane = threadIdx.x & 63;
    if (row >= n) return;
    float x = out[(size_t)row * 64 + lane];
    float m = x;
#pragma unroll
    for (int off = 32; off >= 1; off >>= 1) m = fmaxf(m, __shfl_xor(m, off, 64));
    float ex = expf(x - m);
    float s  = ex;
#pragma unroll
    for (int off = 32; off >= 1; off >>= 1) s += __shfl_xor(s, off, 64);
    out[(size_t)row * 64 + lane] = x - m - logf(s);
}

// ---------------- launch ----------------

extern "C" void kernel_launch(void* const* d_in, const int* in_sizes, int n_in,
                              void* d_out, int out_size, void* d_ws, size_t ws_size,
                              hipStream_t stream) {
    const float* X  = (const float*)d_in[0];
    const int*   ei = (const int*)d_in[1];     // [2][E], int32 per harness convention
    const float* W1 = (const float*)d_in[2];
    const float* b1 = (const float*)d_in[3];
    const float* W2 = (const float*)d_in[4];
    const float* b2 = (const float*)d_in[5];

    const int n = in_sizes[0] / 128;           // 50000
    const int E = in_sizes[1] / 2;             // 800000
    const int* src = ei;
    const int* dst = ei + E;

    char* ws = (char*)d_ws;
    size_t off = 0;
    auto alloc = [&](size_t bytes) -> void* {
        void* p = ws + off;
        off = (off + bytes + 255) & ~(size_t)255;
        return p;
    };
    float* dinv    = (float*)alloc((size_t)n * 4);
    int*   counts  = (int*)  alloc((size_t)n * 4);
    int*   rowptr  = (int*)  alloc((size_t)(n + 1) * 4);
    int*   cursor  = (int*)  alloc((size_t)n * 4);
    int*   bsums   = (int*)  alloc(256 * 4);
    int2*  edges   = (int2*) alloc((size_t)E * 8);
    __half* A      = (__half*)alloc((size_t)n * 128 * 2);   // fp16 GEMM output / gather operand
    float*  B      = (float*) alloc((size_t)n * 128 * 4);   // fp32 agg output / GEMM input

    const int nb = (n + 255) / 256;            // 196 scan blocks

    // --- graph prep (per call; deterministic work) ---
    hipMemsetAsync(counts, 0, (size_t)n * 4, stream);
    count_kernel<<<(E + 255) / 256, 256, 0, stream>>>(dst, E, counts);
    dinv_kernel<<<(n + 255) / 256, 256, 0, stream>>>(counts, dinv, n);
    block_sum_kernel<<<nb, 256, 0, stream>>>(counts, n, bsums);
    scan_blocksums_kernel<<<1, 256, 0, stream>>>(bsums, nb);
    scan_write_kernel<<<nb, 256, 0, stream>>>(counts, bsums, n, rowptr, cursor);
    fill_kernel<<<(E + 255) / 256, 256, 0, stream>>>(src, dst, E, dinv, cursor, edges);

    // --- layer 1: A = X@W1 (fp16) ; B = agg(A) + b1 (fp32) ---
    dim3 g1(128 / 64, (n + 63) / 64);
    gemm_k128<<<g1, 256, 0, stream>>>(X, W1, A, n, 128);
    agg_kernel<128, false><<<(n + 7) / 8, 256, 0, stream>>>(A, rowptr, edges, dinv, b1, B, n);

    // --- layer 2: A = B@W1 ; B = relu(agg(A) + b1) ---
    gemm_k128<<<g1, 256, 0, stream>>>(B, W1, A, n, 128);
    agg_kernel<128, true><<<(n + 7) / 8, 256, 0, stream>>>(A, rowptr, edges, dinv, b1, B, n);

    // --- layer 3: A = B@W2 (n x 64, fp16) ; d_out = agg(A) + b2 ; log_softmax in place ---
    dim3 g2(64 / 64, (n + 63) / 64);
    gemm_k128<<<g2, 256, 0, stream>>>(B, W2, A, n, 64);
    agg_kernel<64, false><<<(n + 15) / 16, 256, 0, stream>>>(A, rowptr, edges, dinv, b2,
                                                             (float*)d_out, n);
    logsoftmax_kernel<<<(n + 3) / 4, 256, 0, stream>>>((float*)d_out, n);
}

// Round 4
// 226.424 us; speedup vs baseline: 1.9979x; 1.2564x over previous
//
#include <hip/hip_runtime.h>
#include <hip/hip_fp16.h>
#include <type_traits>

typedef _Float16 f16x8 __attribute__((ext_vector_type(8)));
typedef float    f32x4 __attribute__((ext_vector_type(4)));

__device__ inline unsigned int pack2(float a, float b) {
    __half2 h = __floats2half2_rn(a, b);
    return *(unsigned int*)&h;
}
__device__ inline float2 unpack2(unsigned int u) {
    __half2 h = *(__half2*)&u;
    return __half22float2(h);
}

// ---------------- graph prep ----------------

__global__ void count_kernel(const int* __restrict__ dst, int E, int* __restrict__ counts) {
    int e = blockIdx.x * blockDim.x + threadIdx.x;
    if (e < E) atomicAdd(&counts[dst[e]], 1);
}

__global__ void dinv_kernel(const int* __restrict__ counts, float* __restrict__ dinv, int n) {
    int i = blockIdx.x * blockDim.x + threadIdx.x;
    if (i < n) dinv[i] = rsqrtf(1.0f + (float)counts[i]);   // +1 self loop
}

__global__ __launch_bounds__(256) void block_sum_kernel(const int* __restrict__ counts, int n,
                                                        int* __restrict__ blocksums) {
    __shared__ int s[256];
    int t = threadIdx.x;
    int i = blockIdx.x * 256 + t;
    s[t] = (i < n) ? counts[i] : 0;
    __syncthreads();
#pragma unroll
    for (int off = 128; off >= 1; off >>= 1) {
        if (t < off) s[t] += s[t + off];
        __syncthreads();
    }
    if (t == 0) blocksums[blockIdx.x] = s[0];
}

__global__ __launch_bounds__(256) void scan_blocksums_kernel(int* __restrict__ blocksums, int nb) {
    __shared__ int s[256];
    int t = threadIdx.x;
    int v = (t < nb) ? blocksums[t] : 0;
    s[t] = v;
    __syncthreads();
    for (int off = 1; off < 256; off <<= 1) {
        int u = (t >= off) ? s[t - off] : 0;
        __syncthreads();
        s[t] += u;
        __syncthreads();
    }
    if (t < nb) blocksums[t] = s[t] - v;
}

__global__ __launch_bounds__(256) void scan_write_kernel(const int* __restrict__ counts,
                                                         const int* __restrict__ blockoff, int n,
                                                         int* __restrict__ rowptr,
                                                         int* __restrict__ cursor) {
    __shared__ int s[256];
    int t = threadIdx.x;
    int i = blockIdx.x * 256 + t;
    int v = (i < n) ? counts[i] : 0;
    s[t] = v;
    __syncthreads();
    for (int off = 1; off < 256; off <<= 1) {
        int u = (t >= off) ? s[t - off] : 0;
        __syncthreads();
        s[t] += u;
        __syncthreads();
    }
    int excl = blockoff[blockIdx.x] + s[t] - v;
    if (i < n) {
        rowptr[i] = excl;
        cursor[i] = excl;
        if (i == n - 1) rowptr[n] = excl + v;
    }
}

// packed edge: low 16 bits = src index (n=50000 < 2^16), high 16 = fp16 weight
__global__ void fill_kernel(const int* __restrict__ src, const int* __restrict__ dst, int E,
                            const float* __restrict__ dinv, int* __restrict__ cursor,
                            unsigned int* __restrict__ edges) {
    int e = blockIdx.x * blockDim.x + threadIdx.x;
    if (e < E) {
        int s = src[e], d = dst[e];
        int p = atomicAdd(&cursor[d], 1);
        __half hw = __float2half_rn(dinv[s] * dinv[d]);
        unsigned short ws = *(unsigned short*)&hw;
        edges[p] = (unsigned int)s | ((unsigned int)ws << 16);
    }
}

// ---------------- MFMA GEMM: C[n][DOUT](fp16) = A[n][128] @ W[128][DOUT](fp32) ----------------
// 4 waves/block, 16 rows/wave. Swapped-operand mfma_f32_16x16x32_f16:
//   A-operand = W^T tile from LDS (XOR-swizzled), B-operand = 8 contiguous k per lane from A row.
// D layout: C-row = lane&15, C-cols = nf*16 + (lane>>4)*4 + i  -> 8B packed fp16 store.
template <int DOUT, typename TIN>
__global__ __launch_bounds__(256) void gemm_mfma(const TIN* __restrict__ A,
                                                 const float* __restrict__ W,
                                                 __half* __restrict__ C, int n) {
    constexpr int NF = DOUT / 16;
    __shared__ __align__(16) unsigned char wlds[DOUT * 256];   // Wt[n][k] f16, swizzled

    const int t = threadIdx.x;
    // stage W fp32 [128][DOUT] -> Wt f16 [DOUT][128] (transposed), byte ^= (n&7)<<4
    for (int p = t; p < 64 * DOUT; p += 256) {
        int nn = p % DOUT;
        int k  = (p / DOUT) * 2;
        float w0 = W[(size_t)k * DOUT + nn];
        float w1 = W[(size_t)(k + 1) * DOUT + nn];
        int byte = (nn * 256 + k * 2) ^ ((nn & 7) << 4);
        *(unsigned int*)(wlds + byte) = pack2(w0, w1);
    }
    __syncthreads();

    const int w  = t >> 6;
    const int l  = t & 63;
    const int m  = (blockIdx.x * 4 + w) * 16 + (l & 15);   // output row
    const int kq = l >> 4;                                  // 0..3
    const bool valid = (m < n);

    f32x4 acc[NF];
#pragma unroll
    for (int i = 0; i < NF; ++i) acc[i] = (f32x4){0.f, 0.f, 0.f, 0.f};

#pragma unroll
    for (int ks = 0; ks < 4; ++ks) {
        const int k0 = ks * 32 + kq * 8;
        f16x8 af = {0, 0, 0, 0, 0, 0, 0, 0};
        if (valid) {
            if constexpr (std::is_same<TIN, float>::value) {
                const float4 x0 = *(const float4*)&A[(size_t)m * 128 + k0];
                const float4 x1 = *(const float4*)&A[(size_t)m * 128 + k0 + 4];
                af[0] = (_Float16)x0.x; af[1] = (_Float16)x0.y;
                af[2] = (_Float16)x0.z; af[3] = (_Float16)x0.w;
                af[4] = (_Float16)x1.x; af[5] = (_Float16)x1.y;
                af[6] = (_Float16)x1.z; af[7] = (_Float16)x1.w;
            } else {
                af = *(const f16x8*)&A[(size_t)m * 128 + k0];
            }
        }
#pragma unroll
        for (int nf = 0; nf < NF; ++nf) {
            int nn = nf * 16 + (l & 15);
            int byte = (nn * 256 + k0 * 2) ^ ((nn & 7) << 4);
            f16x8 bf = *(const f16x8*)(wlds + byte);
            acc[nf] = __builtin_amdgcn_mfma_f32_16x16x32_f16(bf, af, acc[nf], 0, 0, 0);
        }
    }

    if (valid) {
#pragma unroll
        for (int nf = 0; nf < NF; ++nf) {
            uint2 o;
            o.x = pack2(acc[nf][0], acc[nf][1]);
            o.y = pack2(acc[nf][2], acc[nf][3]);
            *(uint2*)&C[(size_t)m * DOUT + nf * 16 + kq * 4] = o;
        }
    }
}

// ---------------- aggregation: out[i] = b + H[i]*dinv_i^2 + sum_j w_j*H[col_j] ----------------
// H fp16, 8 features (16B) per lane; optional fused relu / log_softmax.
template <int DOUT, bool RELU, bool LSM, typename TOUT>
__global__ __launch_bounds__(256) void agg_kernel(const __half* __restrict__ H,
                                                  const int* __restrict__ rowptr,
                                                  const unsigned int* __restrict__ edges,
                                                  const float* __restrict__ dinv,
                                                  const float* __restrict__ bias,
                                                  TOUT* __restrict__ out, int n) {
    constexpr int LPR = DOUT / 8;        // lanes per row
    constexpr int RPB = 256 / LPR;       // rows per block
    const int row  = blockIdx.x * RPB + threadIdx.x / LPR;
    const int lane = threadIdx.x % LPR;
    if (row >= n) return;

    const uint4* Hv = (const uint4*)H;   // 16B = 8 halfs

    float a[8];
    {
        const float4 b0 = ((const float4*)bias)[lane * 2];
        const float4 b1 = ((const float4*)bias)[lane * 2 + 1];
        const float di = dinv[row];
        const float sw = di * di;
        uint4 h = Hv[(size_t)row * LPR + lane];
        float2 f;
        f = unpack2(h.x); a[0] = b0.x + f.x * sw; a[1] = b0.y + f.y * sw;
        f = unpack2(h.y); a[2] = b0.z + f.x * sw; a[3] = b0.w + f.y * sw;
        f = unpack2(h.z); a[4] = b1.x + f.x * sw; a[5] = b1.y + f.y * sw;
        f = unpack2(h.w); a[6] = b1.z + f.x * sw; a[7] = b1.w + f.y * sw;
    }

    int j  = rowptr[row];
    const int je = rowptr[row + 1];
    for (; j + 1 < je; j += 2) {
        unsigned int e0 = edges[j], e1 = edges[j + 1];
        unsigned short u0 = (unsigned short)(e0 >> 16), u1 = (unsigned short)(e1 >> 16);
        float w0 = __half2float(*(__half*)&u0);
        float w1 = __half2float(*(__half*)&u1);
        uint4 h0 = Hv[(size_t)(e0 & 0xffffu) * LPR + lane];
        uint4 h1 = Hv[(size_t)(e1 & 0xffffu) * LPR + lane];
        float2 f;
        f = unpack2(h0.x); a[0] += w0 * f.x; a[1] += w0 * f.y;
        f = unpack2(h0.y); a[2] += w0 * f.x; a[3] += w0 * f.y;
        f = unpack2(h0.z); a[4] += w0 * f.x; a[5] += w0 * f.y;
        f = unpack2(h0.w); a[6] += w0 * f.x; a[7] += w0 * f.y;
        f = unpack2(h1.x); a[0] += w1 * f.x; a[1] += w1 * f.y;
        f = unpack2(h1.y); a[2] += w1 * f.x; a[3] += w1 * f.y;
        f = unpack2(h1.z); a[4] += w1 * f.x; a[5] += w1 * f.y;
        f = unpack2(h1.w); a[6] += w1 * f.x; a[7] += w1 * f.y;
    }
    if (j < je) {
        unsigned int e0 = edges[j];
        unsigned short u0 = (unsigned short)(e0 >> 16);
        float w0 = __half2float(*(__half*)&u0);
        uint4 h0 = Hv[(size_t)(e0 & 0xffffu) * LPR + lane];
        float2 f;
        f = unpack2(h0.x); a[0] += w0 * f.x; a[1] += w0 * f.y;
        f = unpack2(h0.y); a[2] += w0 * f.x; a[3] += w0 * f.y;
        f = unpack2(h0.z); a[4] += w0 * f.x; a[5] += w0 * f.y;
        f = unpack2(h0.w); a[6] += w0 * f.x; a[7] += w0 * f.y;
    }

    if (RELU) {
#pragma unroll
        for (int i = 0; i < 8; ++i) a[i] = fmaxf(a[i], 0.f);
    }

    if constexpr (LSM) {
        // log_softmax across the row (LPR lanes * 8 features)
        float m8 = a[0];
#pragma unroll
        for (int i = 1; i < 8; ++i) m8 = fmaxf(m8, a[i]);
#pragma unroll
        for (int off = 1; off < LPR; off <<= 1) m8 = fmaxf(m8, __shfl_xor(m8, off, LPR));
        float s = 0.f;
#pragma unroll
        for (int i = 0; i < 8; ++i) s += expf(a[i] - m8);
#pragma unroll
        for (int off = 1; off < LPR; off <<= 1) s += __shfl_xor(s, off, LPR);
        float ls = m8 + logf(s);
        float* op = (float*)out + (size_t)row * DOUT + lane * 8;
        *(float4*)op       = make_float4(a[0] - ls, a[1] - ls, a[2] - ls, a[3] - ls);
        *(float4*)(op + 4) = make_float4(a[4] - ls, a[5] - ls, a[6] - ls, a[7] - ls);
    } else {
        uint4 o;
        o.x = pack2(a[0], a[1]);
        o.y = pack2(a[2], a[3]);
        o.z = pack2(a[4], a[5]);
        o.w = pack2(a[6], a[7]);
        *(uint4*)&((__half*)out)[(size_t)row * DOUT + lane * 8] = o;
    }
}

// ---------------- launch ----------------

extern "C" void kernel_launch(void* const* d_in, const int* in_sizes, int n_in,
                              void* d_out, int out_size, void* d_ws, size_t ws_size,
                              hipStream_t stream) {
    const float* X  = (const float*)d_in[0];
    const int*   ei = (const int*)d_in[1];
    const float* W1 = (const float*)d_in[2];
    const float* b1 = (const float*)d_in[3];
    const float* W2 = (const float*)d_in[4];
    const float* b2 = (const float*)d_in[5];

    const int n = in_sizes[0] / 128;           // 50000
    const int E = in_sizes[1] / 2;             // 800000
    const int* src = ei;
    const int* dst = ei + E;

    char* ws = (char*)d_ws;
    size_t off = 0;
    auto alloc = [&](size_t bytes) -> void* {
        void* p = ws + off;
        off = (off + bytes + 255) & ~(size_t)255;
        return p;
    };
    float*        dinv   = (float*)alloc((size_t)n * 4);
    int*          counts = (int*)  alloc((size_t)n * 4);
    int*          rowptr = (int*)  alloc((size_t)(n + 1) * 4);
    int*          cursor = (int*)  alloc((size_t)n * 4);
    int*          bsums  = (int*)  alloc(256 * 4);
    unsigned int* edges  = (unsigned int*)alloc((size_t)E * 4);
    __half*       P      = (__half*)alloc((size_t)n * 128 * 2);
    __half*       Q      = (__half*)alloc((size_t)n * 128 * 2);

    const int nb = (n + 255) / 256;

    // --- graph prep ---
    hipMemsetAsync(counts, 0, (size_t)n * 4, stream);
    count_kernel<<<(E + 255) / 256, 256, 0, stream>>>(dst, E, counts);
    dinv_kernel<<<(n + 255) / 256, 256, 0, stream>>>(counts, dinv, n);
    block_sum_kernel<<<nb, 256, 0, stream>>>(counts, n, bsums);
    scan_blocksums_kernel<<<1, 256, 0, stream>>>(bsums, nb);
    scan_write_kernel<<<nb, 256, 0, stream>>>(counts, bsums, n, rowptr, cursor);
    fill_kernel<<<(E + 255) / 256, 256, 0, stream>>>(src, dst, E, dinv, cursor, edges);

    const int gb = (n + 63) / 64;    // gemm blocks (64 rows each)

    // --- layer 1: P = fp16(X@W1); Q = agg(P)+b1 ---
    gemm_mfma<128, float><<<gb, 256, 0, stream>>>(X, W1, P, n);
    agg_kernel<128, false, false, __half><<<(n + 15) / 16, 256, 0, stream>>>(
        P, rowptr, edges, dinv, b1, Q, n);

    // --- layer 2: P = fp16(Q@W1); Q = relu(agg(P)+b1) ---
    gemm_mfma<128, __half><<<gb, 256, 0, stream>>>(Q, W1, P, n);
    agg_kernel<128, true, false, __half><<<(n + 15) / 16, 256, 0, stream>>>(
        P, rowptr, edges, dinv, b1, Q, n);

    // --- layer 3: P = fp16(Q@W2) [n x 64]; d_out = log_softmax(agg(P)+b2) ---
    gemm_mfma<64, __half><<<gb, 256, 0, stream>>>(Q, W2, P, n);
    agg_kernel<64, false, true, float><<<(n + 31) / 32, 256, 0, stream>>>(
        P, rowptr, edges, dinv, b2, (float*)d_out, n);
}

// Round 5
// 182.445 us; speedup vs baseline: 2.4796x; 1.2411x over previous
//
#include <hip/hip_runtime.h>
#include <hip/hip_fp16.h>
#include <type_traits>

typedef _Float16 f16x8 __attribute__((ext_vector_type(8)));
typedef float    f32x4 __attribute__((ext_vector_type(4)));

__device__ inline unsigned int pack2(float a, float b) {
    __half2 h = __floats2half2_rn(a, b);
    return *(unsigned int*)&h;
}
__device__ inline float2 unpack2(unsigned int u) {
    __half2 h = *(__half2*)&u;
    return __half22float2(h);
}

#define MAXB 8192   // staging stride per bucket (mean 4096, sigma ~64 -> safe)

// ---------------- graph prep: bucketed two-phase CSR build ----------------

__global__ void zero_kernel(int* __restrict__ p, int len) {
    int i = blockIdx.x * blockDim.x + threadIdx.x;
    if (i < len) p[i] = 0;
}

// F1: scatter edges into bucket-contiguous staging. record = src(16) | dstlow(8)<<16
__global__ __launch_bounds__(256) void bucket_scatter_kernel(
    const int* __restrict__ src, const int* __restrict__ dst, int E, int nbuck,
    int* __restrict__ bcursor, unsigned int* __restrict__ staging) {
    __shared__ int hist[256];
    __shared__ int base[256];
    const int t = threadIdx.x;
    const int chunk = (E + gridDim.x - 1) / gridDim.x;
    const int e0 = blockIdx.x * chunk;
    const int e1 = min(E, e0 + chunk);
    for (int i = t; i < nbuck; i += 256) hist[i] = 0;
    __syncthreads();
    for (int e = e0 + t; e < e1; e += 256)
        atomicAdd(&hist[((unsigned)dst[e]) >> 8], 1);
    __syncthreads();
    for (int i = t; i < nbuck; i += 256) {
        int c = hist[i];
        base[i] = (c > 0) ? atomicAdd(&bcursor[i], c) : 0;
        hist[i] = 0;                       // reuse as intra-block cursor
    }
    __syncthreads();
    for (int e = e0 + t; e < e1; e += 256) {
        int d = dst[e];
        int b = ((unsigned)d) >> 8;
        int off = atomicAdd(&hist[b], 1);
        staging[(size_t)b * MAXB + base[b] + off] =
            (unsigned)src[e] | ((unsigned)(d & 255) << 16);
    }
}

// F2a: per-bucket node histogram -> counts[] written coalesced (no global atomics)
__global__ __launch_bounds__(256) void bucket_hist_kernel(
    const unsigned int* __restrict__ staging, const int* __restrict__ bcursor,
    int n, int* __restrict__ counts) {
    __shared__ int hist[256];
    const int b = blockIdx.x, t = threadIdx.x;
    hist[t] = 0;
    __syncthreads();
    const int cnt = bcursor[b];
    const unsigned int* rec = staging + (size_t)b * MAXB;
    for (int i = t; i < cnt; i += 256) atomicAdd(&hist[(rec[i] >> 16) & 255], 1);
    __syncthreads();
    int node = (b << 8) + t;
    if (node < n) counts[node] = hist[t];
}

__global__ void dinv_kernel(const int* __restrict__ counts, float* __restrict__ dinv, int n) {
    int i = blockIdx.x * blockDim.x + threadIdx.x;
    if (i < n) dinv[i] = rsqrtf(1.0f + (float)counts[i]);   // +1 self loop
}

// ---- 3-phase device-wide exclusive scan over counts[0..n) -> rowptr ----

__global__ __launch_bounds__(256) void block_sum_kernel(const int* __restrict__ counts, int n,
                                                        int* __restrict__ blocksums) {
    __shared__ int s[256];
    int t = threadIdx.x;
    int i = blockIdx.x * 256 + t;
    s[t] = (i < n) ? counts[i] : 0;
    __syncthreads();
#pragma unroll
    for (int off = 128; off >= 1; off >>= 1) {
        if (t < off) s[t] += s[t + off];
        __syncthreads();
    }
    if (t == 0) blocksums[blockIdx.x] = s[0];
}

__global__ __launch_bounds__(256) void scan_blocksums_kernel(int* __restrict__ blocksums, int nb) {
    __shared__ int s[256];
    int t = threadIdx.x;
    int v = (t < nb) ? blocksums[t] : 0;
    s[t] = v;
    __syncthreads();
    for (int off = 1; off < 256; off <<= 1) {
        int u = (t >= off) ? s[t - off] : 0;
        __syncthreads();
        s[t] += u;
        __syncthreads();
    }
    if (t < nb) blocksums[t] = s[t] - v;
}

__global__ __launch_bounds__(256) void scan_write_kernel(const int* __restrict__ counts,
                                                         const int* __restrict__ blockoff, int n,
                                                         int* __restrict__ rowptr) {
    __shared__ int s[256];
    int t = threadIdx.x;
    int i = blockIdx.x * 256 + t;
    int v = (i < n) ? counts[i] : 0;
    s[t] = v;
    __syncthreads();
    for (int off = 1; off < 256; off <<= 1) {
        int u = (t >= off) ? s[t - off] : 0;
        __syncthreads();
        s[t] += u;
        __syncthreads();
    }
    int excl = blockoff[blockIdx.x] + s[t] - v;
    if (i < n) {
        rowptr[i] = excl;
        if (i == n - 1) rowptr[n] = excl + v;
    }
}

// F2b: place records at exact CSR positions; final edge = src(16) | fp16 weight << 16
__global__ __launch_bounds__(256) void bucket_place_kernel(
    const unsigned int* __restrict__ staging, const int* __restrict__ bcursor,
    const int* __restrict__ rowptr, const float* __restrict__ dinv, int n,
    unsigned int* __restrict__ edges) {
    __shared__ int lcur[256];
    const int b = blockIdx.x, t = threadIdx.x;
    int node = (b << 8) + t;
    lcur[t] = rowptr[min(node, n)];
    __syncthreads();
    const int cnt = bcursor[b];
    const unsigned int* rec = staging + (size_t)b * MAXB;
    for (int i = t; i < cnt; i += 256) {
        unsigned r = rec[i];
        int dl = (r >> 16) & 255;
        int s  = r & 0xffff;
        int p  = atomicAdd(&lcur[dl], 1);
        __half hw = __float2half_rn(dinv[s] * dinv[(b << 8) + dl]);
        unsigned short ws = *(unsigned short*)&hw;
        edges[p] = (unsigned)s | ((unsigned)ws << 16);
    }
}

// ---------------- MFMA GEMM: C[n][DOUT](fp16) = A[n][128] @ W[128][DOUT](fp32) ----------------
template <int DOUT, typename TIN>
__global__ __launch_bounds__(256) void gemm_mfma(const TIN* __restrict__ A,
                                                 const float* __restrict__ W,
                                                 __half* __restrict__ C, int n) {
    constexpr int NF = DOUT / 16;
    __shared__ __align__(16) unsigned char wlds[DOUT * 256];   // Wt[n][k] f16, swizzled

    const int t = threadIdx.x;
    for (int p = t; p < 64 * DOUT; p += 256) {
        int nn = p % DOUT;
        int k  = (p / DOUT) * 2;
        float w0 = W[(size_t)k * DOUT + nn];
        float w1 = W[(size_t)(k + 1) * DOUT + nn];
        int byte = (nn * 256 + k * 2) ^ ((nn & 7) << 4);
        *(unsigned int*)(wlds + byte) = pack2(w0, w1);
    }
    __syncthreads();

    const int w  = t >> 6;
    const int l  = t & 63;
    const int m  = (blockIdx.x * 4 + w) * 16 + (l & 15);   // output row
    const int kq = l >> 4;                                  // 0..3
    const bool valid = (m < n);

    f32x4 acc[NF];
#pragma unroll
    for (int i = 0; i < NF; ++i) acc[i] = (f32x4){0.f, 0.f, 0.f, 0.f};

#pragma unroll
    for (int ks = 0; ks < 4; ++ks) {
        const int k0 = ks * 32 + kq * 8;
        f16x8 af = {0, 0, 0, 0, 0, 0, 0, 0};
        if (valid) {
            if constexpr (std::is_same<TIN, float>::value) {
                const float4 x0 = *(const float4*)&A[(size_t)m * 128 + k0];
                const float4 x1 = *(const float4*)&A[(size_t)m * 128 + k0 + 4];
                af[0] = (_Float16)x0.x; af[1] = (_Float16)x0.y;
                af[2] = (_Float16)x0.z; af[3] = (_Float16)x0.w;
                af[4] = (_Float16)x1.x; af[5] = (_Float16)x1.y;
                af[6] = (_Float16)x1.z; af[7] = (_Float16)x1.w;
            } else {
                af = *(const f16x8*)&A[(size_t)m * 128 + k0];
            }
        }
#pragma unroll
        for (int nf = 0; nf < NF; ++nf) {
            int nn = nf * 16 + (l & 15);
            int byte = (nn * 256 + k0 * 2) ^ ((nn & 7) << 4);
            f16x8 bf = *(const f16x8*)(wlds + byte);
            acc[nf] = __builtin_amdgcn_mfma_f32_16x16x32_f16(bf, af, acc[nf], 0, 0, 0);
        }
    }

    if (valid) {
#pragma unroll
        for (int nf = 0; nf < NF; ++nf) {
            uint2 o;
            o.x = pack2(acc[nf][0], acc[nf][1]);
            o.y = pack2(acc[nf][2], acc[nf][3]);
            *(uint2*)&C[(size_t)m * DOUT + nf * 16 + kq * 4] = o;
        }
    }
}

// ---------------- aggregation: out[i] = b + H[i]*dinv_i^2 + sum_j w_j*H[col_j] ----------------
template <int DOUT, bool RELU, bool LSM, typename TOUT>
__global__ __launch_bounds__(256) void agg_kernel(const __half* __restrict__ H,
                                                  const int* __restrict__ rowptr,
                                                  const unsigned int* __restrict__ edges,
                                                  const float* __restrict__ dinv,
                                                  const float* __restrict__ bias,
                                                  TOUT* __restrict__ out, int n) {
    constexpr int LPR = DOUT / 8;        // lanes per row
    constexpr int RPB = 256 / LPR;       // rows per block
    const int row  = blockIdx.x * RPB + threadIdx.x / LPR;
    const int lane = threadIdx.x % LPR;
    if (row >= n) return;

    const uint4* Hv = (const uint4*)H;   // 16B = 8 halfs

    float a[8];
    {
        const float4 b0 = ((const float4*)bias)[lane * 2];
        const float4 b1 = ((const float4*)bias)[lane * 2 + 1];
        const float di = dinv[row];
        const float sw = di * di;
        uint4 h = Hv[(size_t)row * LPR + lane];
        float2 f;
        f = unpack2(h.x); a[0] = b0.x + f.x * sw; a[1] = b0.y + f.y * sw;
        f = unpack2(h.y); a[2] = b0.z + f.x * sw; a[3] = b0.w + f.y * sw;
        f = unpack2(h.z); a[4] = b1.x + f.x * sw; a[5] = b1.y + f.y * sw;
        f = unpack2(h.w); a[6] = b1.z + f.x * sw; a[7] = b1.w + f.y * sw;
    }

    int j  = rowptr[row];
    const int je = rowptr[row + 1];
    for (; j + 1 < je; j += 2) {
        unsigned int e0 = edges[j], e1 = edges[j + 1];
        unsigned short u0 = (unsigned short)(e0 >> 16), u1 = (unsigned short)(e1 >> 16);
        float w0 = __half2float(*(__half*)&u0);
        float w1 = __half2float(*(__half*)&u1);
        uint4 h0 = Hv[(size_t)(e0 & 0xffffu) * LPR + lane];
        uint4 h1 = Hv[(size_t)(e1 & 0xffffu) * LPR + lane];
        float2 f;
        f = unpack2(h0.x); a[0] += w0 * f.x; a[1] += w0 * f.y;
        f = unpack2(h0.y); a[2] += w0 * f.x; a[3] += w0 * f.y;
        f = unpack2(h0.z); a[4] += w0 * f.x; a[5] += w0 * f.y;
        f = unpack2(h0.w); a[6] += w0 * f.x; a[7] += w0 * f.y;
        f = unpack2(h1.x); a[0] += w1 * f.x; a[1] += w1 * f.y;
        f = unpack2(h1.y); a[2] += w1 * f.x; a[3] += w1 * f.y;
        f = unpack2(h1.z); a[4] += w1 * f.x; a[5] += w1 * f.y;
        f = unpack2(h1.w); a[6] += w1 * f.x; a[7] += w1 * f.y;
    }
    if (j < je) {
        unsigned int e0 = edges[j];
        unsigned short u0 = (unsigned short)(e0 >> 16);
        float w0 = __half2float(*(__half*)&u0);
        uint4 h0 = Hv[(size_t)(e0 & 0xffffu) * LPR + lane];
        float2 f;
        f = unpack2(h0.x); a[0] += w0 * f.x; a[1] += w0 * f.y;
        f = unpack2(h0.y); a[2] += w0 * f.x; a[3] += w0 * f.y;
        f = unpack2(h0.z); a[4] += w0 * f.x; a[5] += w0 * f.y;
        f = unpack2(h0.w); a[6] += w0 * f.x; a[7] += w0 * f.y;
    }

    if (RELU) {
#pragma unroll
        for (int i = 0; i < 8; ++i) a[i] = fmaxf(a[i], 0.f);
    }

    if constexpr (LSM) {
        float m8 = a[0];
#pragma unroll
        for (int i = 1; i < 8; ++i) m8 = fmaxf(m8, a[i]);
#pragma unroll
        for (int off = 1; off < LPR; off <<= 1) m8 = fmaxf(m8, __shfl_xor(m8, off, LPR));
        float s = 0.f;
#pragma unroll
        for (int i = 0; i < 8; ++i) s += expf(a[i] - m8);
#pragma unroll
        for (int off = 1; off < LPR; off <<= 1) s += __shfl_xor(s, off, LPR);
        float ls = m8 + logf(s);
        float* op = (float*)out + (size_t)row * DOUT + lane * 8;
        *(float4*)op       = make_float4(a[0] - ls, a[1] - ls, a[2] - ls, a[3] - ls);
        *(float4*)(op + 4) = make_float4(a[4] - ls, a[5] - ls, a[6] - ls, a[7] - ls);
    } else {
        uint4 o;
        o.x = pack2(a[0], a[1]);
        o.y = pack2(a[2], a[3]);
        o.z = pack2(a[4], a[5]);
        o.w = pack2(a[6], a[7]);
        *(uint4*)&((__half*)out)[(size_t)row * DOUT + lane * 8] = o;
    }
}

// ---------------- launch ----------------

extern "C" void kernel_launch(void* const* d_in, const int* in_sizes, int n_in,
                              void* d_out, int out_size, void* d_ws, size_t ws_size,
                              hipStream_t stream) {
    const float* X  = (const float*)d_in[0];
    const int*   ei = (const int*)d_in[1];
    const float* W1 = (const float*)d_in[2];
    const float* b1 = (const float*)d_in[3];
    const float* W2 = (const float*)d_in[4];
    const float* b2 = (const float*)d_in[5];

    const int n = in_sizes[0] / 128;           // 50000
    const int E = in_sizes[1] / 2;             // 800000
    const int* src = ei;
    const int* dst = ei + E;
    const int nbuck = (n + 255) >> 8;          // 196

    char* ws = (char*)d_ws;
    size_t off = 0;
    auto alloc = [&](size_t bytes) -> void* {
        void* p = ws + off;
        off = (off + bytes + 255) & ~(size_t)255;
        return p;
    };
    float*        dinv    = (float*)alloc((size_t)n * 4);
    int*          counts  = (int*)  alloc((size_t)n * 4);
    int*          rowptr  = (int*)  alloc((size_t)(n + 1) * 4);
    int*          bcursor = (int*)  alloc((size_t)nbuck * 4);
    int*          bsums   = (int*)  alloc(256 * 4);
    unsigned int* staging = (unsigned int*)alloc((size_t)nbuck * MAXB * 4);
    unsigned int* edges   = (unsigned int*)alloc((size_t)E * 4);
    __half*       P       = (__half*)alloc((size_t)n * 128 * 2);
    __half*       Q       = (__half*)alloc((size_t)n * 128 * 2);

    const int nb = (n + 255) / 256;

    // --- CSR build ---
    zero_kernel<<<1, 256, 0, stream>>>(bcursor, nbuck);
    bucket_scatter_kernel<<<392, 256, 0, stream>>>(src, dst, E, nbuck, bcursor, staging);
    bucket_hist_kernel<<<nbuck, 256, 0, stream>>>(staging, bcursor, n, counts);
    block_sum_kernel<<<nb, 256, 0, stream>>>(counts, n, bsums);
    scan_blocksums_kernel<<<1, 256, 0, stream>>>(bsums, nb);
    scan_write_kernel<<<nb, 256, 0, stream>>>(counts, bsums, n, rowptr);
    dinv_kernel<<<(n + 255) / 256, 256, 0, stream>>>(counts, dinv, n);
    bucket_place_kernel<<<nbuck, 256, 0, stream>>>(staging, bcursor, rowptr, dinv, n, edges);

    const int gb = (n + 63) / 64;

    // --- layer 1: P = fp16(X@W1); Q = agg(P)+b1 ---
    gemm_mfma<128, float><<<gb, 256, 0, stream>>>(X, W1, P, n);
    agg_kernel<128, false, false, __half><<<(n + 15) / 16, 256, 0, stream>>>(
        P, rowptr, edges, dinv, b1, Q, n);

    // --- layer 2: P = fp16(Q@W1); Q = relu(agg(P)+b1) ---
    gemm_mfma<128, __half><<<gb, 256, 0, stream>>>(Q, W1, P, n);
    agg_kernel<128, true, false, __half><<<(n + 15) / 16, 256, 0, stream>>>(
        P, rowptr, edges, dinv, b1, Q, n);

    // --- layer 3: P = fp16(Q@W2) [n x 64]; d_out = log_softmax(agg(P)+b2) ---
    gemm_mfma<64, __half><<<gb, 256, 0, stream>>>(Q, W2, P, n);
    agg_kernel<64, false, true, float><<<(n + 31) / 32, 256, 0, stream>>>(
        P, rowptr, edges, dinv, b2, (float*)d_out, n);
}